// Round 7
// baseline (510.123 us; speedup 1.0000x reference)
//
#include <hip/hip_runtime.h>
#include <math.h>

#define DD 128
#define HH 16
#define CW 32   // dims per chunk
#define NC 4    // chunks
#define EPSV 1e-5f

static __device__ __forceinline__ ushort f2bf(float f) {
  uint u = __float_as_uint(f);
  u += 0x7FFFu + ((u >> 16) & 1u);
  return (ushort)(u >> 16);
}
static __device__ __forceinline__ float bflo(uint u) { return __uint_as_float(u << 16); }
static __device__ __forceinline__ float bfhi(uint u) { return __uint_as_float(u & 0xFFFF0000u); }

// ---------------- CSR build ----------------

__global__ void k_hist(const int* __restrict__ dst, int* __restrict__ deg, int ecnt) {
  int e = blockIdx.x * blockDim.x + threadIdx.x;
  if (e < ecnt) atomicAdd(&deg[dst[e]], 1);
}

__global__ void k_dinv(const int* __restrict__ deg, float* __restrict__ dinv, int n) {
  int i = blockIdx.x * blockDim.x + threadIdx.x;
  if (i < n) dinv[i] = rsqrtf((float)deg[i] + 2.0f);
}

#define SCAN_T 1024
#define SCAN_I 4

__global__ void k_scan1(const int* __restrict__ deg, int* __restrict__ bsum, int n) {
  __shared__ int sh[SCAN_T];
  int tid = threadIdx.x;
  int base = blockIdx.x * SCAN_T * SCAN_I + tid * SCAN_I;
  int s = 0;
#pragma unroll
  for (int j = 0; j < SCAN_I; ++j) { int i = base + j; if (i < n) s += deg[i]; }
  sh[tid] = s;
  __syncthreads();
  for (int off = SCAN_T / 2; off > 0; off >>= 1) {
    if (tid < off) sh[tid] += sh[tid + off];
    __syncthreads();
  }
  if (tid == 0) bsum[blockIdx.x] = sh[0];
}

__global__ void k_scan2(const int* __restrict__ deg, const int* __restrict__ bsum,
                        int* __restrict__ rowoff, int n) {
  __shared__ int sh[SCAN_T];
  __shared__ int sbase;
  int tid = threadIdx.x;
  int b = blockIdx.x;
  if (tid == 0) { int s = 0; for (int j = 0; j < b; ++j) s += bsum[j]; sbase = s; }
  int base = b * SCAN_T * SCAN_I + tid * SCAN_I;
  int d[SCAN_I]; int ts = 0;
#pragma unroll
  for (int j = 0; j < SCAN_I; ++j) { int i = base + j; d[j] = (i < n) ? deg[i] : 0; ts += d[j]; }
  sh[tid] = ts;
  __syncthreads();
  for (int off = 1; off < SCAN_T; off <<= 1) {
    int v = (tid >= off) ? sh[tid - off] : 0;
    __syncthreads();
    sh[tid] += v;
    __syncthreads();
  }
  int ex = sbase + sh[tid] - ts;
#pragma unroll
  for (int j = 0; j < SCAN_I; ++j) {
    int i = base + j;
    if (i < n) rowoff[i] = ex;
    ex += d[j];
  }
}

__global__ void k_fill(const int* __restrict__ src, const int* __restrict__ dst,
                       const float* __restrict__ dinv, const int* __restrict__ rowoff,
                       int* __restrict__ cursor, int2* __restrict__ csr, int ecnt) {
  int e = blockIdx.x * blockDim.x + threadIdx.x;
  if (e >= ecnt) return;
  int s = src[e], d = dst[e];
  int p = atomicAdd(&cursor[d], 1);
  float nw = dinv[s] * dinv[d];
  csr[rowoff[d] + p] = make_int2(s, __float_as_int(nw));
}

// ---------------- GEMM: Cc[chunk][nrows][32] bf16 = A_f32[nrows,128] @ B[128,128] --------

__global__ __launch_bounds__(256) void k_gemm(const float* __restrict__ A,
                                              const float* __restrict__ B,
                                              ushort* __restrict__ C, int nrows) {
  __shared__ float Bs[DD * 64];
  int tid = threadIdx.x;
  int tx = tid & 15, ty = tid >> 4;
  int rowbase = blockIdx.x * 128;
  int c0 = blockIdx.y * 64;
  {
    int kk = tid >> 4;
    int cc = (tid & 15) * 4;
#pragma unroll
    for (int p = 0; p < 8; ++p) {
      int k = p * 16 + kk;
      float4 bv = *reinterpret_cast<const float4*>(&B[k * DD + c0 + cc]);
      *reinterpret_cast<float4*>(&Bs[k * 64 + cc]) = bv;
    }
  }
  __syncthreads();
  float acc[8][4];
#pragma unroll
  for (int i = 0; i < 8; ++i)
#pragma unroll
    for (int j = 0; j < 4; ++j) acc[i][j] = 0.f;
  int rl[8];
#pragma unroll
  for (int i = 0; i < 8; ++i) {
    int r = rowbase + ty * 8 + i;
    rl[i] = (r < nrows) ? r : (nrows - 1);
  }
  const float4* A4 = reinterpret_cast<const float4*>(A);
  for (int kq = 0; kq < 32; ++kq) {
    float4 av[8];
#pragma unroll
    for (int i = 0; i < 8; ++i) av[i] = A4[(size_t)rl[i] * 32 + kq];
#pragma unroll
    for (int j = 0; j < 4; ++j) {
      float4 bv = *reinterpret_cast<const float4*>(&Bs[(kq * 4 + j) * 64 + tx * 4]);
#pragma unroll
      for (int i = 0; i < 8; ++i) {
        float a = (j == 0) ? av[i].x : (j == 1) ? av[i].y : (j == 2) ? av[i].z : av[i].w;
        acc[i][0] = fmaf(a, bv.x, acc[i][0]);
        acc[i][1] = fmaf(a, bv.y, acc[i][1]);
        acc[i][2] = fmaf(a, bv.z, acc[i][2]);
        acc[i][3] = fmaf(a, bv.w, acc[i][3]);
      }
    }
  }
  int cbase = c0 + tx * 4;
  int ch = cbase >> 5, off = cbase & 31;
#pragma unroll
  for (int i = 0; i < 8; ++i) {
    int r = rowbase + ty * 8 + i;
    if (r < nrows) {
      ushort4 o;
      o.x = f2bf(acc[i][0]); o.y = f2bf(acc[i][1]);
      o.z = f2bf(acc[i][2]); o.w = f2bf(acc[i][3]);
      *reinterpret_cast<ushort4*>(&C[((size_t)ch * nrows + r) * CW + off]) = o;
    }
  }
}

// ---------------- chunked edge aggregation: group-per-node, 16-deep ----------------
// Block 256 = 16 groups of 16 lanes; group owns one node's 64B row-chunk (lane = uint,
// 2 dims). 16-deep edge batches: 16 gather instrs x 4 lines(4 groups/wave) = 64 lines
// in flight per wave, all within the 3.2MB L2-resident chunk (chunk-major grid).

__global__ __launch_bounds__(256) void k_aggc(
    const ushort* __restrict__ xwc, const int2* __restrict__ csr,
    const int* __restrict__ rowoff, const int* __restrict__ deg,
    float* __restrict__ agg, int n, int nbpc, int ecnt) {
  int bid = blockIdx.x;
  int c = bid / nbpc;
  int nb = bid - c * nbpc;
  int tid = threadIdx.x;
  int g = tid >> 4, gl = tid & 15;
  int i = nb * 16 + g;
  if (i >= n) i = n - 1;  // duplicate work on last node; benign identical write
  int start = rowoff[i], cnt = deg[i];
  const uint* xc = (const uint*)xwc + (size_t)c * n * 16;
  const int2* cs = csr + (start < ecnt ? start : ecnt - 1);
  // wave-wide max count across the 4 groups sharing this wave
  int m = cnt;
  m = max(m, __shfl_xor(m, 16));
  m = max(m, __shfl_xor(m, 32));
  int it = (m + 15) >> 4;
  float a0 = 0.f, a1 = 0.f;
  for (int b = 0; b < it; ++b) {
    int base = b << 4;
    int2 cc[16];
#pragma unroll
    for (int j = 0; j < 16; ++j) cc[j] = cs[(base + j < cnt) ? base + j : 0];
    uint v[16];
#pragma unroll
    for (int j = 0; j < 16; ++j) v[j] = xc[((uint)cc[j].x << 4) + gl];
#pragma unroll
    for (int j = 0; j < 16; ++j) {
      float nw = (base + j < cnt) ? __int_as_float(cc[j].y) : 0.f;
      a0 = fmaf(bflo(v[j]), nw, a0);
      a1 = fmaf(bfhi(v[j]), nw, a1);
    }
  }
  float2 o; o.x = a0; o.y = a1;
  ((float2*)(agg + (size_t)i * DD + c * CW))[gl] = o;
}

// ---------------- LN epilogues (wave per node) ----------------

__global__ __launch_bounds__(256) void k_ln1(
    const float* __restrict__ agg, const ushort* __restrict__ xwc,
    const float* __restrict__ dinv, const float* __restrict__ bias,
    const float* __restrict__ gam, const float* __restrict__ bet,
    float* __restrict__ outp, int n) {
  int wv = threadIdx.x >> 6, lane = threadIdx.x & 63;
  int i = blockIdx.x * 4 + wv;
  if (i >= n) return;
  int c = lane >> 4, l = lane & 15;
  float di = dinv[i];
  float sw = 2.f * di * di;
  uint su = ((const uint*)xwc)[((size_t)c * n + i) * 16 + l];
  float2 av = ((const float2*)(agg + (size_t)i * DD))[lane];
  float2 bv = ((const float2*)bias)[lane];
  float acc0 = av.x + fmaf(bflo(su), sw, bv.x);
  float acc1 = av.y + fmaf(bfhi(su), sw, bv.y);
  float s = acc0 + acc1;
#pragma unroll
  for (int off = 32; off > 0; off >>= 1) s += __shfl_xor(s, off);
  float mu = s * (1.f / DD);
  float c0 = acc0 - mu, c1 = acc1 - mu;
  float q = c0 * c0 + c1 * c1;
#pragma unroll
  for (int off = 32; off > 0; off >>= 1) q += __shfl_xor(q, off);
  float rstd = rsqrtf(q * (1.f / DD) + EPSV);
  float2 gv = ((const float2*)gam)[lane];
  float2 tv = ((const float2*)bet)[lane];
  float2 o;
  o.x = fmaxf(fmaf(c0 * rstd, gv.x, tv.x), 0.f);
  o.y = fmaxf(fmaf(c1 * rstd, gv.y, tv.y), 0.f);
  ((float2*)(outp + (size_t)i * DD))[lane] = o;
}

__global__ __launch_bounds__(256) void k_ln2(
    const float* __restrict__ agg, const ushort* __restrict__ xwc,
    const float* __restrict__ dinv, const float* __restrict__ bias,
    const float* __restrict__ gam, const float* __restrict__ bet,
    const float* __restrict__ Ws, const float* __restrict__ bs,
    const float* __restrict__ We, const float* __restrict__ be,
    const float* __restrict__ xin, float* __restrict__ outp, int n) {
  int wv = threadIdx.x >> 6, lane = threadIdx.x & 63;
  int i = blockIdx.x * 4 + wv;
  if (i >= n) return;
  int c = lane >> 4, l = lane & 15;
  float di = dinv[i];
  float sw = 2.f * di * di;
  uint su = ((const uint*)xwc)[((size_t)c * n + i) * 16 + l];
  float2 av = ((const float2*)(agg + (size_t)i * DD))[lane];
  float2 bv = ((const float2*)bias)[lane];
  float acc0 = av.x + fmaf(bflo(su), sw, bv.x);
  float acc1 = av.y + fmaf(bfhi(su), sw, bv.y);
  float s = acc0 + acc1;
#pragma unroll
  for (int off = 32; off > 0; off >>= 1) s += __shfl_xor(s, off);
  float mu = s * (1.f / DD);
  float c0 = acc0 - mu, c1 = acc1 - mu;
  float q = c0 * c0 + c1 * c1;
#pragma unroll
  for (int off = 32; off > 0; off >>= 1) q += __shfl_xor(q, off);
  float rstd = rsqrtf(q * (1.f / DD) + EPSV);
  float2 gv = ((const float2*)gam)[lane];
  float2 tv = ((const float2*)bet)[lane];
  float h0 = fmaf(c0 * rstd, gv.x, tv.x);
  float h1 = fmaf(c1 * rstd, gv.y, tv.y);
  // SE gate
  float pj[HH];
  const float* wr0 = &Ws[(2 * lane) * HH];
  const float* wr1 = &Ws[(2 * lane + 1) * HH];
#pragma unroll
  for (int j = 0; j < HH; ++j) pj[j] = h0 * wr0[j] + h1 * wr1[j];
#pragma unroll
  for (int off = 32; off > 0; off >>= 1) {
#pragma unroll
    for (int j = 0; j < HH; ++j) pj[j] += __shfl_xor(pj[j], off);
  }
  float2 bev = ((const float2*)be)[lane];
  float wacc0 = bev.x, wacc1 = bev.y;
#pragma unroll
  for (int j = 0; j < HH; ++j) {
    float sj = fmaxf(pj[j] + bs[j], 0.f);
    float2 wev = ((const float2*)(We + j * DD))[lane];
    wacc0 = fmaf(sj, wev.x, wacc0);
    wacc1 = fmaf(sj, wev.y, wacc1);
  }
  float w0 = 1.f / (1.f + __expf(-wacc0));
  float w1 = 1.f / (1.f + __expf(-wacc1));
  float2 xr = ((const float2*)(xin + (size_t)i * DD))[lane];
  float2 o;
  o.x = fmaxf(fmaf(h0, w0, xr.x), 0.f);
  o.y = fmaxf(fmaf(h1, w1, xr.y), 0.f);
  ((float2*)(outp + (size_t)i * DD))[lane] = o;
}

// ---------------- launcher ----------------

extern "C" void kernel_launch(void* const* d_in, const int* in_sizes, int n_in,
                              void* d_out, int out_size, void* d_ws, size_t ws_size,
                              hipStream_t stream) {
  const float* x   = (const float*)d_in[0];
  const int*   ei  = (const int*)d_in[1];
  const float* W1  = (const float*)d_in[2];
  const float* b1  = (const float*)d_in[3];
  const float* g1  = (const float*)d_in[4];
  const float* be1 = (const float*)d_in[5];
  const float* W2  = (const float*)d_in[6];
  const float* b2  = (const float*)d_in[7];
  const float* g2  = (const float*)d_in[8];
  const float* be2 = (const float*)d_in[9];
  const float* Ws  = (const float*)d_in[10];
  const float* bs  = (const float*)d_in[11];
  const float* We  = (const float*)d_in[12];
  const float* bee = (const float*)d_in[13];
  float* outp = (float*)d_out;

  int n    = in_sizes[0] / DD;
  int ecnt = in_sizes[1] / 2;
  const int* src = ei;
  const int* dst = ei + ecnt;

  char* w = (char*)d_ws;
  ushort* xwc   = (ushort*)w; w += (size_t)n * DD * 2;
  float*  h1    = (float*)w;  w += (size_t)n * DD * 4;
  float*  agg   = (float*)w;  w += (size_t)n * DD * 4;
  int*    deg   = (int*)w;    w += (size_t)n * 4;
  int*    cursor= (int*)w;    w += (size_t)n * 4;  // adjacent to deg (one memset)
  int*    rowoff= (int*)w;    w += (size_t)n * 4;
  float*  dinv  = (float*)w;  w += (size_t)n * 4;
  int*    bsum  = (int*)w;    w += 64 * 4;
  int2*   csr   = (int2*)w;   w += (size_t)ecnt * 8;

  hipMemsetAsync(deg, 0, (size_t)n * 8, stream);  // deg + cursor

  const int TB = 256;
  int eb = (ecnt + TB - 1) / TB;
  int nbk = (n + TB - 1) / TB;
  k_hist<<<eb, TB, 0, stream>>>(dst, deg, ecnt);
  k_dinv<<<nbk, TB, 0, stream>>>(deg, dinv, n);
  int nb = (n + SCAN_T * SCAN_I - 1) / (SCAN_T * SCAN_I);
  k_scan1<<<nb, SCAN_T, 0, stream>>>(deg, bsum, n);
  k_scan2<<<nb, SCAN_T, 0, stream>>>(deg, bsum, rowoff, n);
  k_fill<<<eb, TB, 0, stream>>>(src, dst, dinv, rowoff, cursor, csr, ecnt);

  dim3 gg((n + 127) / 128, 2);
  int nb4  = (n + 3) / 4;     // blocks for wave-per-node kernels
  int nbpc = (n + 15) / 16;   // blocks per chunk for aggc
  int aggblocks = nbpc * NC;

  k_gemm<<<gg, 256, 0, stream>>>(x, W1, xwc, n);
  k_aggc<<<aggblocks, 256, 0, stream>>>(xwc, csr, rowoff, deg, agg, n, nbpc, ecnt);
  k_ln1<<<nb4, 256, 0, stream>>>(agg, xwc, dinv, b1, g1, be1, h1, n);
  k_gemm<<<gg, 256, 0, stream>>>(h1, W2, xwc, n);
  k_aggc<<<aggblocks, 256, 0, stream>>>(xwc, csr, rowoff, deg, agg, n, nbpc, ecnt);
  k_ln2<<<nb4, 256, 0, stream>>>(agg, xwc, dinv, b2, g2, be2,
                                 Ws, bs, We, bee, x, outp, n);
}

// Round 8
// 394.014 us; speedup vs baseline: 1.2947x; 1.2947x over previous
//
#include <hip/hip_runtime.h>
#include <math.h>

#define DD 128
#define HH 16
#define EPSV 1e-5f

static __device__ __forceinline__ ushort f2bf(float f) {
  uint u = __float_as_uint(f);
  u += 0x7FFFu + ((u >> 16) & 1u);
  return (ushort)(u >> 16);
}
static __device__ __forceinline__ float bflo(uint u) { return __uint_as_float(u << 16); }
static __device__ __forceinline__ float bfhi(uint u) { return __uint_as_float(u & 0xFFFF0000u); }

// ---------------- CSR build ----------------

__global__ void k_hist(const int* __restrict__ dst, int* __restrict__ deg, int ecnt) {
  int e = blockIdx.x * blockDim.x + threadIdx.x;
  if (e < ecnt) atomicAdd(&deg[dst[e]], 1);
}

__global__ void k_dinv(const int* __restrict__ deg, float* __restrict__ dinv, int n) {
  int i = blockIdx.x * blockDim.x + threadIdx.x;
  if (i < n) dinv[i] = rsqrtf((float)deg[i] + 2.0f);
}

#define SCAN_T 1024
#define SCAN_I 4

__global__ void k_scan1(const int* __restrict__ deg, int* __restrict__ bsum, int n) {
  __shared__ int sh[SCAN_T];
  int tid = threadIdx.x;
  int base = blockIdx.x * SCAN_T * SCAN_I + tid * SCAN_I;
  int s = 0;
#pragma unroll
  for (int j = 0; j < SCAN_I; ++j) { int i = base + j; if (i < n) s += deg[i]; }
  sh[tid] = s;
  __syncthreads();
  for (int off = SCAN_T / 2; off > 0; off >>= 1) {
    if (tid < off) sh[tid] += sh[tid + off];
    __syncthreads();
  }
  if (tid == 0) bsum[blockIdx.x] = sh[0];
}

__global__ void k_scan2(const int* __restrict__ deg, const int* __restrict__ bsum,
                        int* __restrict__ rowoff, int n) {
  __shared__ int sh[SCAN_T];
  __shared__ int sbase;
  int tid = threadIdx.x;
  int b = blockIdx.x;
  if (tid == 0) { int s = 0; for (int j = 0; j < b; ++j) s += bsum[j]; sbase = s; }
  int base = b * SCAN_T * SCAN_I + tid * SCAN_I;
  int d[SCAN_I]; int ts = 0;
#pragma unroll
  for (int j = 0; j < SCAN_I; ++j) { int i = base + j; d[j] = (i < n) ? deg[i] : 0; ts += d[j]; }
  sh[tid] = ts;
  __syncthreads();
  for (int off = 1; off < SCAN_T; off <<= 1) {
    int v = (tid >= off) ? sh[tid - off] : 0;
    __syncthreads();
    sh[tid] += v;
    __syncthreads();
  }
  int ex = sbase + sh[tid] - ts;
#pragma unroll
  for (int j = 0; j < SCAN_I; ++j) {
    int i = base + j;
    if (i < n) rowoff[i] = ex;
    ex += d[j];
  }
}

__global__ void k_fill(const int* __restrict__ src, const int* __restrict__ dst,
                       const float* __restrict__ dinv, const int* __restrict__ rowoff,
                       int* __restrict__ cursor, int2* __restrict__ csr, int ecnt) {
  int e = blockIdx.x * blockDim.x + threadIdx.x;
  if (e >= ecnt) return;
  int s = src[e], d = dst[e];
  int p = atomicAdd(&cursor[d], 1);
  float nw = dinv[s] * dinv[d];
  csr[rowoff[d] + p] = make_int2(s, __float_as_int(nw));
}

// ---------------- GEMM: C_bf16[nrows,128] = A_f32[nrows,128] @ B[128,128] ----------------

__global__ __launch_bounds__(256) void k_gemm(const float* __restrict__ A,
                                              const float* __restrict__ B,
                                              ushort* __restrict__ C, int nrows) {
  __shared__ float Bs[DD * 64];
  int tid = threadIdx.x;
  int tx = tid & 15, ty = tid >> 4;
  int rowbase = blockIdx.x * 128;
  int c0 = blockIdx.y * 64;
  {
    int kk = tid >> 4;
    int cc = (tid & 15) * 4;
#pragma unroll
    for (int p = 0; p < 8; ++p) {
      int k = p * 16 + kk;
      float4 bv = *reinterpret_cast<const float4*>(&B[k * DD + c0 + cc]);
      *reinterpret_cast<float4*>(&Bs[k * 64 + cc]) = bv;
    }
  }
  __syncthreads();
  float acc[8][4];
#pragma unroll
  for (int i = 0; i < 8; ++i)
#pragma unroll
    for (int j = 0; j < 4; ++j) acc[i][j] = 0.f;
  int rl[8];
#pragma unroll
  for (int i = 0; i < 8; ++i) {
    int r = rowbase + ty * 8 + i;
    rl[i] = (r < nrows) ? r : (nrows - 1);
  }
  const float4* A4 = reinterpret_cast<const float4*>(A);
  for (int kq = 0; kq < 32; ++kq) {
    float4 av[8];
#pragma unroll
    for (int i = 0; i < 8; ++i) av[i] = A4[(size_t)rl[i] * 32 + kq];
#pragma unroll
    for (int j = 0; j < 4; ++j) {
      float4 bv = *reinterpret_cast<const float4*>(&Bs[(kq * 4 + j) * 64 + tx * 4]);
#pragma unroll
      for (int i = 0; i < 8; ++i) {
        float a = (j == 0) ? av[i].x : (j == 1) ? av[i].y : (j == 2) ? av[i].z : av[i].w;
        acc[i][0] = fmaf(a, bv.x, acc[i][0]);
        acc[i][1] = fmaf(a, bv.y, acc[i][1]);
        acc[i][2] = fmaf(a, bv.z, acc[i][2]);
        acc[i][3] = fmaf(a, bv.w, acc[i][3]);
      }
    }
  }
  int cbase = c0 + tx * 4;
#pragma unroll
  for (int i = 0; i < 8; ++i) {
    int r = rowbase + ty * 8 + i;
    if (r < nrows) {
      ushort4 o;
      o.x = f2bf(acc[i][0]); o.y = f2bf(acc[i][1]);
      o.z = f2bf(acc[i][2]); o.w = f2bf(acc[i][3]);
      *reinterpret_cast<ushort4*>(&C[(size_t)r * DD + cbase]) = o;
    }
  }
}

// ---------------- edge accumulate: forced 8-deep gather pipeline ----------------
// Wave = node i; lane owns dims {2*lane, 2*lane+1} (one packed uint of the 256B row).
// CSR pointer/count wave-uniform (readfirstlane) -> entries load via s_load into SGPRs.
// sched_barrier(0) fences pin ISA order: [8 gathers][next-8 CSR][16 FMAs] so the wave
// keeps 8 row-gathers (32 cache lines) in flight instead of a load->use serial chain.

static __device__ __forceinline__ void edge_accum(
    const uint* __restrict__ xw32, const int2* __restrict__ csr,
    int start, int cnt, uint lane, float& acc0, float& acc1) {
  const int2* cs = csr + __builtin_amdgcn_readfirstlane(start);
  int rem = __builtin_amdgcn_readfirstlane(cnt);
  int2 c[8];
  if (rem >= 8) {
#pragma unroll
    for (int j = 0; j < 8; ++j) c[j] = cs[j];
    cs += 8;
  }
  while (rem >= 16) {
    uint v[8];
#pragma unroll
    for (int j = 0; j < 8; ++j) v[j] = xw32[((uint)c[j].x << 6) + lane];
    __builtin_amdgcn_sched_barrier(0);   // all 8 gathers issued first
    int2 cn[8];
#pragma unroll
    for (int j = 0; j < 8; ++j) cn[j] = cs[j];
    __builtin_amdgcn_sched_barrier(0);   // CSR prefetch under the gathers
#pragma unroll
    for (int j = 0; j < 8; ++j) {
      float nw = __int_as_float(c[j].y);
      acc0 = fmaf(bflo(v[j]), nw, acc0);
      acc1 = fmaf(bfhi(v[j]), nw, acc1);
    }
#pragma unroll
    for (int j = 0; j < 8; ++j) c[j] = cn[j];
    cs += 8; rem -= 8;
  }
  if (rem >= 8) {  // consume the preloaded batch
    uint v[8];
#pragma unroll
    for (int j = 0; j < 8; ++j) v[j] = xw32[((uint)c[j].x << 6) + lane];
    __builtin_amdgcn_sched_barrier(0);
#pragma unroll
    for (int j = 0; j < 8; ++j) {
      float nw = __int_as_float(c[j].y);
      acc0 = fmaf(bflo(v[j]), nw, acc0);
      acc1 = fmaf(bfhi(v[j]), nw, acc1);
    }
    rem -= 8;
  }
  if (rem > 0) {  // tail < 8: issue all 8 slots, zero-weight the inactive ones
    int2 ct[8];
#pragma unroll
    for (int j = 0; j < 8; ++j) ct[j] = cs[j < rem ? j : 0];
    uint v[8];
#pragma unroll
    for (int j = 0; j < 8; ++j) v[j] = xw32[((uint)ct[j].x << 6) + lane];
    __builtin_amdgcn_sched_barrier(0);
#pragma unroll
    for (int j = 0; j < 8; ++j) {
      float nw = (j < rem) ? __int_as_float(ct[j].y) : 0.f;
      acc0 = fmaf(bflo(v[j]), nw, acc0);
      acc1 = fmaf(bfhi(v[j]), nw, acc1);
    }
  }
}

// ---------------- agg1: gather bf16 + self + bias + LN + ReLU -> fp32 h1 ----------------

__global__ __launch_bounds__(256) void k_agg1(
    const ushort* __restrict__ xw, const int2* __restrict__ csr,
    const int* __restrict__ rowoff, const int* __restrict__ deg,
    const float* __restrict__ dinv, const float* __restrict__ bias,
    const float* __restrict__ gam, const float* __restrict__ bet,
    float* __restrict__ outp, int n) {
  int wv = threadIdx.x >> 6, lane = threadIdx.x & 63;
  int i = blockIdx.x * 4 + wv;
  if (i >= n) return;
  int start = rowoff[i], cnt = deg[i];
  float di = dinv[i];
  const uint* xw32 = (const uint*)xw;
  float2 bv = ((const float2*)bias)[lane];
  uint su = xw32[((uint)i << 6) + lane];
  float sw = 2.f * di * di;
  float acc0 = fmaf(bflo(su), sw, bv.x);
  float acc1 = fmaf(bfhi(su), sw, bv.y);
  edge_accum(xw32, csr, start, cnt, (uint)lane, acc0, acc1);
  // LayerNorm over 128 dims (wave-local)
  float s = acc0 + acc1;
#pragma unroll
  for (int off = 32; off > 0; off >>= 1) s += __shfl_xor(s, off);
  float mu = s * (1.f / DD);
  float c0 = acc0 - mu, c1 = acc1 - mu;
  float q = c0 * c0 + c1 * c1;
#pragma unroll
  for (int off = 32; off > 0; off >>= 1) q += __shfl_xor(q, off);
  float rstd = rsqrtf(q * (1.f / DD) + EPSV);
  float2 gv = ((const float2*)gam)[lane];
  float2 tv = ((const float2*)bet)[lane];
  float h0 = fmaf(c0 * rstd, gv.x, tv.x);
  float h1 = fmaf(c1 * rstd, gv.y, tv.y);
  float2 o;
  o.x = fmaxf(h0, 0.f);
  o.y = fmaxf(h1, 0.f);
  ((float2*)(outp + (size_t)i * DD))[lane] = o;
}

// ---------------- agg2: gather + LN + SE + residual + ReLU -> fp32 out ----------------

__global__ __launch_bounds__(256) void k_agg2(
    const ushort* __restrict__ xw, const int2* __restrict__ csr,
    const int* __restrict__ rowoff, const int* __restrict__ deg,
    const float* __restrict__ dinv, const float* __restrict__ bias,
    const float* __restrict__ gam, const float* __restrict__ bet,
    const float* __restrict__ Ws, const float* __restrict__ bs,
    const float* __restrict__ We, const float* __restrict__ be,
    const float* __restrict__ xin, float* __restrict__ outp, int n) {
  int wv = threadIdx.x >> 6, lane = threadIdx.x & 63;
  int i = blockIdx.x * 4 + wv;
  if (i >= n) return;
  int start = rowoff[i], cnt = deg[i];
  float di = dinv[i];
  const uint* xw32 = (const uint*)xw;
  float2 bv = ((const float2*)bias)[lane];
  uint su = xw32[((uint)i << 6) + lane];
  float sw = 2.f * di * di;
  float acc0 = fmaf(bflo(su), sw, bv.x);
  float acc1 = fmaf(bfhi(su), sw, bv.y);
  edge_accum(xw32, csr, start, cnt, (uint)lane, acc0, acc1);
  // LayerNorm
  float s = acc0 + acc1;
#pragma unroll
  for (int off = 32; off > 0; off >>= 1) s += __shfl_xor(s, off);
  float mu = s * (1.f / DD);
  float c0 = acc0 - mu, c1 = acc1 - mu;
  float q = c0 * c0 + c1 * c1;
#pragma unroll
  for (int off = 32; off > 0; off >>= 1) q += __shfl_xor(q, off);
  float rstd = rsqrtf(q * (1.f / DD) + EPSV);
  float2 gv = ((const float2*)gam)[lane];
  float2 tv = ((const float2*)bet)[lane];
  float h0 = fmaf(c0 * rstd, gv.x, tv.x);
  float h1 = fmaf(c1 * rstd, gv.y, tv.y);
  // SE: s16 = relu(h @ Ws + bs); w = sigmoid(s16 @ We + be)
  float pj[HH];
  const float* wr0 = &Ws[(2 * lane) * HH];
  const float* wr1 = &Ws[(2 * lane + 1) * HH];
#pragma unroll
  for (int j = 0; j < HH; ++j) pj[j] = h0 * wr0[j] + h1 * wr1[j];
#pragma unroll
  for (int off = 32; off > 0; off >>= 1) {
#pragma unroll
    for (int j = 0; j < HH; ++j) pj[j] += __shfl_xor(pj[j], off);
  }
  float2 bev = ((const float2*)be)[lane];
  float wacc0 = bev.x, wacc1 = bev.y;
#pragma unroll
  for (int j = 0; j < HH; ++j) {
    float sj = fmaxf(pj[j] + bs[j], 0.f);
    float2 wev = ((const float2*)(We + j * DD))[lane];
    wacc0 = fmaf(sj, wev.x, wacc0);
    wacc1 = fmaf(sj, wev.y, wacc1);
  }
  float w0 = 1.f / (1.f + __expf(-wacc0));
  float w1 = 1.f / (1.f + __expf(-wacc1));
  float2 xr = ((const float2*)(xin + (size_t)i * DD))[lane];
  float2 o;
  o.x = fmaxf(fmaf(h0, w0, xr.x), 0.f);
  o.y = fmaxf(fmaf(h1, w1, xr.y), 0.f);
  ((float2*)(outp + (size_t)i * DD))[lane] = o;
}

// ---------------- launcher ----------------

extern "C" void kernel_launch(void* const* d_in, const int* in_sizes, int n_in,
                              void* d_out, int out_size, void* d_ws, size_t ws_size,
                              hipStream_t stream) {
  const float* x   = (const float*)d_in[0];
  const int*   ei  = (const int*)d_in[1];
  const float* W1  = (const float*)d_in[2];
  const float* b1  = (const float*)d_in[3];
  const float* g1  = (const float*)d_in[4];
  const float* be1 = (const float*)d_in[5];
  const float* W2  = (const float*)d_in[6];
  const float* b2  = (const float*)d_in[7];
  const float* g2  = (const float*)d_in[8];
  const float* be2 = (const float*)d_in[9];
  const float* Ws  = (const float*)d_in[10];
  const float* bs  = (const float*)d_in[11];
  const float* We  = (const float*)d_in[12];
  const float* bee = (const float*)d_in[13];
  float* outp = (float*)d_out;

  int n    = in_sizes[0] / DD;
  int ecnt = in_sizes[1] / 2;
  const int* src = ei;
  const int* dst = ei + ecnt;

  char* w = (char*)d_ws;
  ushort* xw    = (ushort*)w; w += (size_t)n * DD * 2;
  float*  h1    = (float*)w;  w += (size_t)n * DD * 4;
  int*    deg   = (int*)w;    w += (size_t)n * 4;
  int*    cursor= (int*)w;    w += (size_t)n * 4;  // adjacent to deg (one memset)
  int*    rowoff= (int*)w;    w += (size_t)n * 4;
  float*  dinv  = (float*)w;  w += (size_t)n * 4;
  int*    bsum  = (int*)w;    w += 64 * 4;
  int2*   csr   = (int2*)w;   w += ((size_t)ecnt + 16) * 8;  // +16: tail batch overread pad

  hipMemsetAsync(deg, 0, (size_t)n * 8, stream);  // deg + cursor

  const int TB = 256;
  int eb = (ecnt + TB - 1) / TB;
  int nbk = (n + TB - 1) / TB;
  k_hist<<<eb, TB, 0, stream>>>(dst, deg, ecnt);
  k_dinv<<<nbk, TB, 0, stream>>>(deg, dinv, n);
  int nb = (n + SCAN_T * SCAN_I - 1) / (SCAN_T * SCAN_I);
  k_scan1<<<nb, SCAN_T, 0, stream>>>(deg, bsum, n);
  k_scan2<<<nb, SCAN_T, 0, stream>>>(deg, bsum, rowoff, n);
  k_fill<<<eb, TB, 0, stream>>>(src, dst, dinv, rowoff, cursor, csr, ecnt);

  dim3 gg((n + 127) / 128, 2);
  int nb4 = (n + 3) / 4;
  k_gemm<<<gg, 256, 0, stream>>>(x, W1, xw, n);
  k_agg1<<<nb4, 256, 0, stream>>>(xw, csr, rowoff, deg, dinv, b1, g1, be1, h1, n);
  k_gemm<<<gg, 256, 0, stream>>>(h1, W2, xw, n);
  k_agg2<<<nb4, 256, 0, stream>>>(xw, csr, rowoff, deg, dinv, b2, g2, be2,
                                  Ws, bs, We, bee, x, outp, n);
}